// Round 1
// baseline (498.085 us; speedup 1.0000x reference)
//
#include <hip/hip_runtime.h>

#define S_SPAT 262144   // 64^3
#define NCH 64

// ws float offsets (all scratch < 10KB)
#define WS_XM    0      // [2][64] masked channel sums
#define WS_MH    128    // [2][64]
#define WS_MW    256    // [2][64]
#define WS_MD    384    // [2][64]
#define WS_NPIX  512    // [2]
#define WS_CBIAS 516    // [2]
#define WS_M     518    // [2]
#define WS_COEF  520    // [2]  npix/S
#define WS_WQE   528    // [2][64] effective logit weights (incl /8)
#define WS_QH    656    // [2][64]
#define WS_QW    784    // [2][64]
#define WS_QD    912    // [2][64]
#define WS_QUERY 1040   // [2][64]
#define WS_BLKM  1280   // [512]
#define WS_BLKS  1792   // [512]

__device__ inline float waveReduceSum(float v) {
#pragma unroll
    for (int o = 32; o > 0; o >>= 1) v += __shfl_xor(v, o, 64);
    return v;
}
__device__ inline float waveReduceMax(float v) {
#pragma unroll
    for (int o = 32; o > 0; o >>= 1) v = fmaxf(v, __shfl_xor(v, o, 64));
    return v;
}

// ---- mask stats: maskH/maskW/maskD per batch. 128 blocks (b,h), 256 thr ----
__global__ void k_mask_stats(const float* __restrict__ mask, float* __restrict__ ws) {
    int bid = blockIdx.x;
    int b = bid >> 6, h = bid & 63;
    int t = threadIdx.x;
    const float* mp = mask + (size_t)b * S_SPAT + h * 4096;
    float vals[16];
    float sum = 0.f;
#pragma unroll
    for (int j = 0; j < 16; j++) { vals[j] = mp[j * 256 + t]; sum += vals[j]; }
    // element index j*256+t: d = t&63 (fixed per thread), w = 4j + (t>>6)
    __shared__ float ldsD[64];
    __shared__ float ldsW[64];
    __shared__ float wsum[4];
    if (t < 64) { ldsD[t] = 0.f; ldsW[t] = 0.f; }
    __syncthreads();
    int wv = t >> 6, lane = t & 63;
    atomicAdd(&ldsD[lane], sum);
#pragma unroll
    for (int j = 0; j < 16; j++) {
        float w_s = waveReduceSum(vals[j]);
        if (lane == 0) atomicAdd(&ldsW[4 * j + wv], w_s);
    }
    float tot = waveReduceSum(sum);
    if (lane == 0) wsum[wv] = tot;
    __syncthreads();
    if (t == 0) ws[WS_MH + b * 64 + h] = wsum[0] + wsum[1] + wsum[2] + wsum[3];
    if (t < 64) {
        atomicAdd(&ws[WS_MD + b * 64 + t], ldsD[t]);
        atomicAdd(&ws[WS_MW + b * 64 + t], ldsW[t]);
    }
}

// ---- xm[b,c] = sum_s mask*x. 8192 blocks = (b,c,chunk64), 256 thr ----
__global__ void k_xm(const float* __restrict__ x, const float* __restrict__ mask,
                     float* __restrict__ ws) {
    int bid = blockIdx.x;
    int chunk = bid & 63;
    int bc = bid >> 6;            // b*64+c
    int b = bc >> 6;
    int t = threadIdx.x;
    const float4* xp = (const float4*)(x + (size_t)bc * S_SPAT + chunk * 4096);
    const float4* mp = (const float4*)(mask + (size_t)b * S_SPAT + chunk * 4096);
    float acc = 0.f;
#pragma unroll
    for (int j = 0; j < 4; j++) {
        float4 xv = xp[j * 256 + t];
        float4 mv = mp[j * 256 + t];
        acc += xv.x * mv.x + xv.y * mv.y + xv.z * mv.z + xv.w * mv.w;
    }
    __shared__ float wsum[4];
    float tot = waveReduceSum(acc);
    int wv = t >> 6, lane = t & 63;
    if (lane == 0) wsum[wv] = tot;
    __syncthreads();
    if (t == 0) atomicAdd(&ws[WS_XM + bc], wsum[0] + wsum[1] + wsum[2] + wsum[3]);
}

// ---- tiny: query -> effective weights. 1 block, 64 threads ----
__global__ void k_query(const float* __restrict__ Wk, const float* __restrict__ bk,
                        const float* __restrict__ Wq, const float* __restrict__ bq,
                        const float* __restrict__ h_tab, const float* __restrict__ w_tab,
                        const float* __restrict__ d_tab, float* __restrict__ ws) {
    int k = threadIdx.x;  // 0..63
    __shared__ float q_l[2][64];
    for (int b = 0; b < 2; b++) {
        float npix = 0.f;
        for (int h = 0; h < 64; h++) npix += ws[WS_MH + b * 64 + h];
        float acc = bq[k] * npix;
        for (int c = 0; c < 64; c++) acc += Wq[k * 64 + c] * ws[WS_XM + b * 64 + c];
        for (int h = 0; h < 64; h++) acc += h_tab[h * 64 + k] * ws[WS_MH + b * 64 + h];
        for (int w = 0; w < 64; w++) acc += w_tab[w * 64 + k] * ws[WS_MW + b * 64 + w];
        for (int d = 0; d < 64; d++) acc += d_tab[d * 64 + k] * ws[WS_MD + b * 64 + d];
        float q = acc / npix;
        q_l[b][k] = q;
        ws[WS_QUERY + b * 64 + k] = q;
        if (k == 0) ws[WS_NPIX + b] = npix;
    }
    __syncthreads();
    const float inv8 = 0.125f;  // 1/sqrt(64)
    for (int b = 0; b < 2; b++) {
        float we = 0.f, qh = 0.f, qw = 0.f, qd = 0.f, cb = 0.f;
        for (int kk = 0; kk < 64; kk++) {
            float q = q_l[b][kk];
            we += q * Wk[kk * 64 + k];
            qh += q * h_tab[k * 64 + kk];
            qw += q * w_tab[k * 64 + kk];
            qd += q * d_tab[k * 64 + kk];
            cb += q * bk[kk];
        }
        ws[WS_WQE + b * 64 + k] = we * inv8;
        ws[WS_QH + b * 64 + k] = qh * inv8;
        ws[WS_QW + b * 64 + k] = qw * inv8;
        ws[WS_QD + b * 64 + k] = qd * inv8;
        if (k == 0) ws[WS_CBIAS + b] = cb * inv8;
    }
}

// ---- logits + per-block softmax partials. 512 blocks, 256 thr, 4 vox/thr ----
__global__ void k_logits(const float* __restrict__ x, float* __restrict__ logit_buf,
                         float* __restrict__ ws) {
    int bid = blockIdx.x;
    int b = bid >> 8;
    int s0 = (bid & 255) * 1024 + threadIdx.x * 4;
    const float* xb = x + (size_t)b * NCH * S_SPAT;
    float4 acc = {0.f, 0.f, 0.f, 0.f};
#pragma unroll
    for (int c = 0; c < 64; c++) {
        float wv = ws[WS_WQE + b * 64 + c];  // uniform -> s_load
        float4 xv = *(const float4*)(xb + (size_t)c * S_SPAT + s0);
        acc.x += wv * xv.x; acc.y += wv * xv.y; acc.z += wv * xv.z; acc.w += wv * xv.w;
    }
    int h = s0 >> 12, w = (s0 >> 6) & 63, d0 = s0 & 63;
    float base = ws[WS_CBIAS + b] + ws[WS_QH + b * 64 + h] + ws[WS_QW + b * 64 + w];
    float4 qd = *(const float4*)(&ws[WS_QD + b * 64 + d0]);
    float4 lg = {acc.x + base + qd.x, acc.y + base + qd.y,
                 acc.z + base + qd.z, acc.w + base + qd.w};
    *(float4*)(&logit_buf[(size_t)b * S_SPAT + s0]) = lg;

    __shared__ float red[4];
    int wv = threadIdx.x >> 6, lane = threadIdx.x & 63;
    float m = fmaxf(fmaxf(lg.x, lg.y), fmaxf(lg.z, lg.w));
    float wm = waveReduceMax(m);
    if (lane == 0) red[wv] = wm;
    __syncthreads();
    float mb = fmaxf(fmaxf(red[0], red[1]), fmaxf(red[2], red[3]));
    float e = __expf(lg.x - mb) + __expf(lg.y - mb) + __expf(lg.z - mb) + __expf(lg.w - mb);
    __syncthreads();
    float es = waveReduceSum(e);
    if (lane == 0) red[wv] = es;
    __syncthreads();
    if (threadIdx.x == 0) {
        ws[WS_BLKM + bid] = mb;
        ws[WS_BLKS + bid] = red[0] + red[1] + red[2] + red[3];
    }
}

// ---- combine block partials -> M, coef = npix/S. 2 blocks, 256 thr ----
__global__ void k_softmax_reduce(float* __restrict__ ws) {
    int b = blockIdx.x;
    int t = threadIdx.x;
    float m = ws[WS_BLKM + b * 256 + t];
    float s = ws[WS_BLKS + b * 256 + t];
    __shared__ float red[4];
    int wv = t >> 6, lane = t & 63;
    float wm = waveReduceMax(m);
    if (lane == 0) red[wv] = wm;
    __syncthreads();
    float M = fmaxf(fmaxf(red[0], red[1]), fmaxf(red[2], red[3]));
    float contrib = s * __expf(m - M);
    __syncthreads();
    float cs = waveReduceSum(contrib);
    if (lane == 0) red[wv] = cs;
    __syncthreads();
    if (t == 0) {
        float S = red[0] + red[1] + red[2] + red[3];
        ws[WS_M + b] = M;
        ws[WS_COEF + b] = ws[WS_NPIX + b] / S;
    }
}

// ---- out[b,co,s] = coef * exp(logit - M) * (Wv.x + bv). 1 voxel/thread ----
__global__ void __launch_bounds__(256) k_out(const float* __restrict__ x,
                                             const float* __restrict__ Wv,
                                             const float* __restrict__ bv,
                                             const float* __restrict__ logit_buf,
                                             const float* __restrict__ ws,
                                             float* __restrict__ out) {
    int v = blockIdx.x * 256 + threadIdx.x;  // 0..524287
    int b = v >> 18;
    int s = v & (S_SPAT - 1);
    float a = ws[WS_COEF + b] * __expf(logit_buf[v] - ws[WS_M + b]);
    const float* xb = x + (size_t)b * NCH * S_SPAT + s;
    float xr[64];
#pragma unroll
    for (int c = 0; c < 64; c++) xr[c] = xb[(size_t)c * S_SPAT];
    float* ob = out + (size_t)b * NCH * S_SPAT + s;
#pragma unroll 4
    for (int co = 0; co < 64; co++) {
        float acc = bv[co];
#pragma unroll
        for (int c = 0; c < 64; c++) acc = fmaf(Wv[co * 64 + c], xr[c], acc);
        ob[(size_t)co * S_SPAT] = a * acc;
    }
}

// ---- copy mask into the tail of d_out (also overwrites logit scratch) ----
__global__ void k_copy_mask(const float* __restrict__ mask, float* __restrict__ out_tail) {
    int i = blockIdx.x * 256 + threadIdx.x;
    ((float4*)out_tail)[i] = ((const float4*)mask)[i];
}

extern "C" void kernel_launch(void* const* d_in, const int* in_sizes, int n_in,
                              void* d_out, int out_size, void* d_ws, size_t ws_size,
                              hipStream_t stream) {
    const float* x     = (const float*)d_in[0];
    const float* mask  = (const float*)d_in[1];
    const float* Wk    = (const float*)d_in[2];
    const float* bk    = (const float*)d_in[3];
    const float* Wv    = (const float*)d_in[4];
    const float* bv    = (const float*)d_in[5];
    const float* Wq    = (const float*)d_in[6];
    const float* bq    = (const float*)d_in[7];
    const float* h_tab = (const float*)d_in[8];
    const float* w_tab = (const float*)d_in[9];
    const float* d_tab = (const float*)d_in[10];
    float* ws  = (float*)d_ws;
    float* out = (float*)d_out;
    // logits staged in the mask-slot of d_out (overwritten last by k_copy_mask)
    float* logit_buf = out + (size_t)2 * NCH * S_SPAT;

    hipMemsetAsync(ws, 0, 1024 * sizeof(float), stream);  // zero atomic targets
    k_mask_stats<<<128, 256, 0, stream>>>(mask, ws);
    k_xm<<<8192, 256, 0, stream>>>(x, mask, ws);
    k_query<<<1, 64, 0, stream>>>(Wk, bk, Wq, bq, h_tab, w_tab, d_tab, ws);
    k_logits<<<512, 256, 0, stream>>>(x, logit_buf, ws);
    k_softmax_reduce<<<2, 256, 0, stream>>>(ws);
    k_out<<<2048, 256, 0, stream>>>(x, Wv, bv, logit_buf, ws, out);
    k_copy_mask<<<512, 256, 0, stream>>>(mask, out + (size_t)2 * NCH * S_SPAT);
}